// Round 5
// baseline (111.515 us; speedup 1.0000x reference)
//
#include <hip/hip_runtime.h>
#include <hip/hip_bf16.h>

#define EPSV 1e-5f
#define PITCH 36                 // shorts per pcol (32 ci + 4 pad) = 72 B
#define TILE_SH (66 * PITCH)     // shorts per parity array per wave
#define WTILE_SH (2 * TILE_SH)   // 4752 shorts = 9504 B per wave

typedef short bf16x8 __attribute__((ext_vector_type(8)));
typedef short bf16x4 __attribute__((ext_vector_type(4)));
typedef float f32x4  __attribute__((ext_vector_type(4)));

__device__ __forceinline__ short f2bf(float f){
  unsigned u = __float_as_uint(f);
  u += 0x7fff + ((u >> 16) & 1);     // RNE
  return (short)(u >> 16);
}
__device__ __forceinline__ int pk2(float a, float b){
  __hip_bfloat162 h = __float22bfloat162_rn(float2{a, b});
  return *reinterpret_cast<int*>(&h);
}

// ---------------------------------------------------------------------------
// Kernel A: Wb[b][j][co][ci] = bf16(conv_w[co][ci][j] + scale * (B@A)[b][co][ci*5+j])
// ---------------------------------------------------------------------------
__global__ void build_weights(const float* __restrict__ A_flat,
                              const float* __restrict__ B_flat,
                              const float* __restrict__ conv_w,
                              const float* __restrict__ scale_p,
                              short* __restrict__ Wb){
  int idx = blockIdx.x * 256 + threadIdx.x;   // ((b*5+j)*128 + co)*64 + ci
  int ci = idx & 63;
  int co = (idx >> 6) & 127;
  int bj = idx >> 13;          // 0..159
  int b  = bj / 5;
  int j  = bj - 5 * b;
  int m  = ci * 5 + j;
  const float* Bp = B_flat + (b * 128 + co) * 8;
  const float* Ap = A_flat + b * 8 * 320 + m;
  float d = 0.f;
#pragma unroll
  for (int r = 0; r < 8; ++r) d = fmaf(Bp[r], Ap[r * 320], d);
  float w = conv_w[co * 320 + m] + scale_p[0] * d;
  Wb[idx] = f2bf(w);
}

// ---------------------------------------------------------------------------
// Kernel B: block = (sample, group), 512 thr / 8 waves, 2 blocks/CU.
// Each wave owns 128 out-t and stages its OWN private parity-split LDS tile
// (9.5 KB) per (ci-chunk, t-half) phase -> NO barriers until the GroupNorm
// reduction. Waves run decorrelated; latency hidden by 16 free waves/CU.
// Swizzle: 4 group-blocks of a sample are 8 bids apart -> same XCD (R2: 67MB).
// ---------------------------------------------------------------------------
__global__ __launch_bounds__(512, 4)
void conv_gn_mfma(const float* __restrict__ x,
                  const short* __restrict__ Wb,
                  const float* __restrict__ conv_b,
                  const float* __restrict__ gamma,
                  const float* __restrict__ beta,
                  float* __restrict__ out){
  __shared__ short xt[8 * WTILE_SH];          // 76032 B, per-wave private slices
  __shared__ float redS[8], redQ[8], bc2[2];

  const int bid    = blockIdx.x;
  const int sample = ((bid & 7) << 5) + (bid >> 5);  // R2 swizzle
  const int g      = (bid >> 3) & 3;
  const int b      = sample >> 3;
  const int tid    = threadIdx.x;
  const int lane   = tid & 63;
  const int wid    = tid >> 6;          // 0..7
  const int l16    = lane & 15;
  const int lk     = lane >> 4;         // 0..3

  short* xe = xt + wid * WTILE_SH;      // this wave's even-col tile
  short* xo = xe + TILE_SH;             // this wave's odd-col tile

  f32x4 acc[2][8];
#pragma unroll
  for (int m2 = 0; m2 < 2; ++m2)
#pragma unroll
    for (int n = 0; n < 8; ++n) acc[m2][n] = (f32x4){0.f,0.f,0.f,0.f};

  const size_t wb_base = (size_t)b * 5 * 128 * 64;
  const float* xsamp = x + (size_t)sample * 64 * 2048;

#pragma unroll
  for (int ph = 0; ph < 4; ++ph) {
    const int ch = ph >> 1;             // ci chunk (ch-major: weight reuse)
    const int th = ph & 1;              // t-half
    const int T0 = th * 512 + wid * 64; // wave's out-t base
    // tile origin: pcol0 <-> x-col 2*T0-2 (even) / 2*T0-1 (odd)

    const float* xb = xsamp + (size_t)(ch * 32) * 2048;

    // ---- stage wave-private tile (no block barriers)
    {
      // main: lane l covers x-cols 2*T0+2l, +1  -> pe(l+1), po(l+1); always in-bounds
      const int c = 2 * T0 + 2 * (int)lane;
#pragma unroll
      for (int rg = 0; rg < 8; ++rg) {
        const float* r = xb + (size_t)(rg * 4) * 2048 + c;
        float2 v0 = *(const float2*)(r);
        float2 v1 = *(const float2*)(r + 2048);
        float2 v2 = *(const float2*)(r + 4096);
        float2 v3 = *(const float2*)(r + 6144);
        int2 ev = { pk2(v0.x, v1.x), pk2(v2.x, v3.x) };
        int2 od = { pk2(v0.y, v1.y), pk2(v2.y, v3.y) };
        *(int2*)(xe + (lane + 1) * PITCH + rg * 4) = ev;
        *(int2*)(xo + (lane + 1) * PITCH + rg * 4) = od;
      }
      // halos (wave-uniform predicates): pe0/po0 = x-cols 2T0-2,-1 ; pe65 = 2T0+128
      if (lane < 32) {
        const int ci = lane;
        float2 h{0.f, 0.f};
        if (T0 > 0) h = *(const float2*)(xb + (size_t)ci * 2048 + (2 * T0 - 2));
        xe[ci] = f2bf(h.x);              // pcol 0
        xo[ci] = f2bf(h.y);
      } else {
        const int ci = lane - 32;
        const int xc = 2 * T0 + 128;
        float v = (xc < 2048) ? xb[(size_t)ci * 2048 + xc] : 0.f;
        xe[65 * PITCH + ci] = f2bf(v);
      }
    }

    // ---- compute from own tile (compiler inserts lgkmcnt; no barrier needed)
#pragma unroll
    for (int j = 0; j < 5; ++j) {
      const short* apb = Wb + wb_base + (size_t)(j * 128 + g * 32) * 64 + ch * 32 + lk * 8;
      bf16x8 a0 = *(const bf16x8*)(apb + (size_t)l16 * 64);
      bf16x8 a1 = *(const bf16x8*)(apb + (size_t)(l16 + 16) * 64);
      const short* arr = (j & 1) ? xo : xe;
      const int joff = (j & 1) ? ((j - 1) >> 1) : (j >> 1);
#pragma unroll
      for (int nn = 0; nn < 4; ++nn) {
        int tl = nn * 16 + l16;                      // t within wave range
        const short* bp = arr + (tl + joff) * PITCH + lk * 8;
        bf16x4 lo = *(const bf16x4*)bp;
        bf16x4 hi = *(const bf16x4*)(bp + 4);
        bf16x8 bfr = {lo[0],lo[1],lo[2],lo[3],hi[0],hi[1],hi[2],hi[3]};
        const int n = th * 4 + nn;                   // static (ph unrolled)
        acc[0][n] = __builtin_amdgcn_mfma_f32_16x16x32_bf16(a0, bfr, acc[0][n], 0, 0, 0);
        acc[1][n] = __builtin_amdgcn_mfma_f32_16x16x32_bf16(a1, bfr, acc[1][n], 0, 0, 0);
      }
    }
  }

  // ---- epilogue: bias + ReLU + GroupNorm over 32co x 1024t
  float cb_[2][4], ga_[2][4], be_[2][4];
#pragma unroll
  for (int m2 = 0; m2 < 2; ++m2)
#pragma unroll
    for (int r = 0; r < 4; ++r) {
      int co = g * 32 + m2 * 16 + lk * 4 + r;
      cb_[m2][r] = conv_b[co];
      ga_[m2][r] = gamma[co];
      be_[m2][r] = beta[co];
    }
  float s1 = 0.f, s2 = 0.f;
#pragma unroll
  for (int m2 = 0; m2 < 2; ++m2)
#pragma unroll
    for (int n = 0; n < 8; ++n)
#pragma unroll
      for (int r = 0; r < 4; ++r) {
        float v = acc[m2][n][r] + cb_[m2][r];
        v = v > 0.f ? v : 0.f;
        acc[m2][n][r] = v;
        s1 += v;
        s2 = fmaf(v, v, s2);
      }
#pragma unroll
  for (int off = 32; off; off >>= 1) {
    s1 += __shfl_down(s1, off);
    s2 += __shfl_down(s2, off);
  }
  if (lane == 0) { redS[wid] = s1; redQ[wid] = s2; }
  __syncthreads();
  if (tid == 0) {
    float a = 0.f, q = 0.f;
#pragma unroll
    for (int w = 0; w < 8; ++w) { a += redS[w]; q += redQ[w]; }
    float mean = a * (1.f / 32768.f);
    float var  = q * (1.f / 32768.f) - mean * mean;
    bc2[0] = mean;
    bc2[1] = rsqrtf(var + EPSV);
  }
  __syncthreads();
  const float mean = bc2[0], inv = bc2[1];
  float* ob = out + (size_t)sample * 128 * 1024;
#pragma unroll
  for (int m2 = 0; m2 < 2; ++m2)
#pragma unroll
    for (int r = 0; r < 4; ++r) {
      int co = g * 32 + m2 * 16 + lk * 4 + r;
      float aa = ga_[m2][r] * inv;
      float bb = be_[m2][r] - mean * aa;
      float* orow = ob + (size_t)co * 1024 + l16;
#pragma unroll
      for (int n = 0; n < 8; ++n) {
        int t = (n >> 2) * 512 + wid * 64 + (n & 3) * 16;
        orow[t] = acc[m2][n][r] * aa + bb;
      }
    }
}

// ---------------------------------------------------------------------------
extern "C" void kernel_launch(void* const* d_in, const int* in_sizes, int n_in,
                              void* d_out, int out_size, void* d_ws, size_t ws_size,
                              hipStream_t stream) {
  const float* x       = (const float*)d_in[0];
  const float* A_flat  = (const float*)d_in[1];
  const float* B_flat  = (const float*)d_in[2];
  const float* conv_w  = (const float*)d_in[3];
  const float* conv_b  = (const float*)d_in[4];
  const float* gamma   = (const float*)d_in[5];
  const float* beta    = (const float*)d_in[6];
  const float* scale_p = (const float*)d_in[9];

  float* out = (float*)d_out;
  short* Wb  = (short*)d_ws;   // 32*5*128*64 bf16 = 2.62 MB

  build_weights<<<5120, 256, 0, stream>>>(A_flat, B_flat, conv_w, scale_p, Wb);
  conv_gn_mfma<<<1024, 512, 0, stream>>>(x, Wb, conv_b, gamma, beta, out);
}